// Round 8
// baseline (174.658 us; speedup 1.0000x reference)
//
#include <hip/hip_runtime.h>

// Problem constants (fixed by reference)
#define BB 16
#define SS 1024
#define NIN 7
#define NHID 28
#define NH 7
#define DH 4

// Raw 2^x (v_exp_f32). exp(x) == exp2(x*log2e); log2e folded into Q scales.
#define EXP2F(x) __builtin_amdgcn_exp2f(x)

// Packed fp32 (VOP3P v_pk_mul_f32 / v_pk_fma_f32).
typedef float v2f __attribute__((ext_vector_type(2)));
__device__ __forceinline__ v2f pkfma(v2f a, v2f b, v2f c) {
    return __builtin_elementwise_fma(a, b, c);
}
__device__ __forceinline__ v2f lo2(float4 a) { v2f r; r.x = a.x; r.y = a.y; return r; }
__device__ __forceinline__ v2f hi2(float4 a) { v2f r; r.x = a.z; r.y = a.w; return r; }
__device__ __forceinline__ v2f splat2(float s) { v2f r; r.x = s; r.y = s; return r; }

constexpr int ROWS = BB * SS;                 // 16384
constexpr int QKV_ELEMS = BB * NH * SS * DH;  // 458752 floats per tensor
constexpr int CHUNK_STRIDE = BB * NH * SS;    // 114688: per-ks-chunk stride (f4 / f1 units)

// ---------------------------------------------------------------------------
// Kernel 1 (fused): attention 1 WITH in-block QKV projection.
//
// R7 post-mortem: quad-consecutive ownership made LDS writes a 64B/lane
// stride -> 2.06M bank-conflict cycles (32-way on ds_write_b128), costing
// more than the coalesced x-loads saved. REVERTED to R6's interleaved
// (r*64+ql) ownership + scalar global x loads + SGPR weights (0 conflicts).
//
// R8 (on top of the revert): transposed-K packed dot. K stored in LDS as
// KT[d][kp] = (K[2kp][d], K[2kp+1][d]) so one pk chain scores TWO keys:
//   t1 = pk_fma(qz,kt2, pk_mul(qx,kt0)); t2 = pk_fma(qw,kt3, pk_mul(qy,kt1));
//   s2 = t1 + t2   ->  s2.x = (qx kx + qz kz) + (qy ky + qw kw)
// EXACTLY the prior per-key association -> bit-identical scores; l and V
// accumulation keep sequential per-key order -> absmax must stay exactly
// 0.001953125. Saves the 2 scalar horizontal adds per key pair (inner
// VALU 12 -> 11 instr / 2 keys; attn1 is ~85% inner-issue-bound, model
// calibrated R4-R7). Q-component splats are loop-invariant (hoisted).
// KT written via consecutive-dword ds_write_b32 (conflict-free).
//
// Structure: split-K x4, grid = 112 bh x 4 qt x 4 ks = 1792 == 7/CU.
// 8 waves x 32-key slices, 4 q/thread interleaved, broadcast ds_read;
// in-block 8-slice merge; unnormalized per-(q,ks) partials to scratch in
// the out2 region (k_attn2 overwrites it later). 3 barriers.
// ---------------------------------------------------------------------------
__global__ __launch_bounds__(512) void k_attn1(
    const float* __restrict__ inp,
    const float* __restrict__ Wq, const float* __restrict__ bq,
    const float* __restrict__ Wk, const float* __restrict__ bk,
    const float* __restrict__ Wv, const float* __restrict__ bv,
    float4* __restrict__ Apart, float* __restrict__ Lpart)
{
    __shared__ char smem[40960];
    float*  KTf  = (float*)smem;              // [4][256] floats: KT[d][key] 4 KB
    float4* Vsh  = (float4*)(smem + 4096);    // [256]   4 KB (phase 1)
    float4* pacc = (float4*)smem;             // [8][256] 32 KB (phase 2 overlay)
    float*  pl   = (float*)(smem + 32768);    // [8][256]  8 KB

    const int bh  = blockIdx.x >> 4;          // 0..111
    const int qt  = (blockIdx.x >> 2) & 3;    // q tile (256 queries)
    const int ks  = blockIdx.x & 3;           // key chunk (256 keys)
    const int tid = threadIdx.x;
    const int b   = bh / NH, h = bh % NH;

    const int ql = tid & 63;
    const int kq = tid >> 6;          // wave id; uniform within wave

    // ---- cooperative K/V projection straight from global x (L1/L2-hot):
    //      threads 0-255 -> K key tid (writes transposed), 256-511 -> V.
    //      Weight/bias indices are block-uniform -> s_load (SGPR).
    {
        const int half = __builtin_amdgcn_readfirstlane(tid >> 8);  // 0:K 1:V
        const int key  = tid & 255;
        const float* xr = inp + (size_t)(b * SS + (ks << 8) + key) * NIN;
        const float* W  = half ? Wv : Wk;
        const float4 bias = ((const float4*)(half ? bv : bk))[h];
        v2f alo = lo2(bias), ahi = hi2(bias);
        #pragma unroll
        for (int i = 0; i < NIN; ++i) {
            const v2f xi2 = splat2(xr[i]);
            const float4 w = ((const float4*)W)[i * NH + h];   // uniform -> SGPR
            alo = pkfma(xi2, lo2(w), alo);
            ahi = pkfma(xi2, hi2(w), ahi);
        }
        if (half == 0) {
            // transposed store: KT[d][key]; consecutive lanes -> consecutive
            // dwords per instruction (conflict-free)
            KTf[0 * 256 + key] = alo.x;
            KTf[1 * 256 + key] = alo.y;
            KTf[2 * 256 + key] = ahi.x;
            KTf[3 * 256 + key] = ahi.y;
        } else {
            Vsh[key] = make_float4(alo.x, alo.y, ahi.x, ahi.y);
        }
    }

    // ---- per-thread Q projection for the 4 owned queries (interleaved
    //      rows r*64+ql; independent of LDS -> overlaps K/V writes).
    const float qs_scale = 0.5f * 1.4426950408889634f;  // (1/sqrt(4)) * log2(e)
    const v2f qs2 = splat2(qs_scale);
    const float4 bq4 = ((const float4*)bq)[h];           // uniform -> SGPR
    v2f qlo[4], qhi[4];
    #pragma unroll
    for (int r = 0; r < 4; ++r) {
        const float* xr = inp + (size_t)(b * SS + (qt << 8) + r * 64 + ql) * NIN;
        v2f alo = lo2(bq4), ahi = hi2(bq4);
        #pragma unroll
        for (int i = 0; i < NIN; ++i) {
            const v2f xi2 = splat2(xr[i]);
            const float4 w = ((const float4*)Wq)[i * NH + h]; // uniform -> SGPR
            alo = pkfma(xi2, lo2(w), alo);
            ahi = pkfma(xi2, hi2(w), ahi);
        }
        qlo[r] = alo * qs2;
        qhi[r] = ahi * qs2;
    }

    // loop-invariant component splats (v_pk op_sel or one-time movs)
    v2f qx2[4], qy2[4], qz2[4], qw2[4];
    #pragma unroll
    for (int r = 0; r < 4; ++r) {
        qx2[r] = splat2(qlo[r].x); qy2[r] = splat2(qlo[r].y);
        qz2[r] = splat2(qhi[r].x); qw2[r] = splat2(qhi[r].y);
    }
    __syncthreads();   // K/V visible to all waves

    v2f alo[4], ahi[4];
    float l[4];
    #pragma unroll
    for (int r = 0; r < 4; ++r) {
        alo[r] = splat2(0.f); ahi[r] = splat2(0.f); l[r] = 0.f;
    }

    const v2f* KT = (const v2f*)smem;   // [4][128] key-pairs
    const int kp0 = kq << 4;            // 16 key-pairs = 32 keys per wave
    #pragma unroll 4
    for (int kp = kp0; kp < kp0 + 16; ++kp) {
        const v2f kt0 = KT[        kp];   // broadcast addrs (wave-uniform)
        const v2f kt1 = KT[128 +   kp];
        const v2f kt2 = KT[256 +   kp];
        const v2f kt3 = KT[384 +   kp];
        const float4 v0 = Vsh[2 * kp];
        const float4 v1 = Vsh[2 * kp + 1];
        const v2f v0lo = lo2(v0), v0hi = hi2(v0);
        const v2f v1lo = lo2(v1), v1hi = hi2(v1);
        #pragma unroll
        for (int r = 0; r < 4; ++r) {
            v2f t1 = pkfma(qz2[r], kt2, qx2[r] * kt0);
            v2f t2 = pkfma(qw2[r], kt3, qy2[r] * kt1);
            const v2f s2 = t1 + t2;       // per-key association == previous
            const float p0 = EXP2F(s2.x);
            l[r] += p0;
            alo[r] = pkfma(splat2(p0), v0lo, alo[r]);
            ahi[r] = pkfma(splat2(p0), v0hi, ahi[r]);
            const float p1 = EXP2F(s2.y);
            l[r] += p1;
            alo[r] = pkfma(splat2(p1), v1lo, alo[r]);
            ahi[r] = pkfma(splat2(p1), v1hi, ahi[r]);
        }
    }

    __syncthreads();   // all K/V reads done; smem reused as merge buffers
    #pragma unroll
    for (int r = 0; r < 4; ++r) {
        pacc[kq * 256 + r * 64 + ql] = make_float4(alo[r].x, alo[r].y,
                                                   ahi[r].x, ahi[r].y);
        pl[kq * 256 + r * 64 + ql]   = l[r];
    }
    __syncthreads();

    // merge the 8 k-slices: threads 0..255 own query qt*256 + tid
    if (tid < 256) {
        float4 a0 = pacc[tid];
        v2f mlo = lo2(a0), mhi = hi2(a0);
        float ll = pl[tid];
        #pragma unroll
        for (int j = 1; j < 8; ++j) {
            const float4 t = pacc[j * 256 + tid];
            mlo = mlo + lo2(t);               // v_pk_add_f32, per-comp order
            mhi = mhi + hi2(t);
            ll += pl[j * 256 + tid];
        }
        // unnormalized partial for this 256-key chunk; coalesced in q
        const size_t o = ((size_t)(ks * (BB * NH) + bh) << 10) + (qt << 8) + tid;
        Apart[o] = make_float4(mlo.x, mlo.y, mhi.x, mhi.y);
        Lpart[o] = ll;
    }
}

// ---------------------------------------------------------------------------
// Kernel 3: reduce the 4 split-K partials + normalize (softmax denominator),
// then LayerNorm(28) + FFN(28->7)+ReLU+residual -> out (output 0),
// then Q2 (row-major, pre-scaled by (1/sqrt(7))*log2e for exp2 softmax)
// and K2 TRANSPOSED: K2T[b][d][s].
// ---------------------------------------------------------------------------
__global__ __launch_bounds__(256) void k_lnffn(
    const float4* __restrict__ Apart, const float* __restrict__ Lpart,
    const float* __restrict__ inp,
    const float* __restrict__ lnw, const float* __restrict__ lnb,
    const float* __restrict__ W1, const float* __restrict__ b1,
    const float* __restrict__ Wq2, const float* __restrict__ bq2,
    const float* __restrict__ Wk2, const float* __restrict__ bk2,
    float* __restrict__ outp, float* __restrict__ Q2, float* __restrict__ K2T)
{
    const int r = blockIdx.x * 256 + threadIdx.x;
    const int b = r >> 10, s = r & 1023;

    float y[NHID];
    float mu = 0.f;
    #pragma unroll
    for (int h = 0; h < NH; ++h) {
        const size_t base = ((size_t)(b * NH + h) << 10) + s;
        float4 a  = Apart[base];
        float  ll = Lpart[base];
        #pragma unroll
        for (int c = 1; c < 4; ++c) {
            float4 t = Apart[base + (size_t)c * CHUNK_STRIDE];
            a.x += t.x; a.y += t.y; a.z += t.z; a.w += t.w;
            ll += Lpart[base + (size_t)c * CHUNK_STRIDE];
        }
        const float inv = 1.f / ll;
        y[4 * h + 0] = a.x * inv; y[4 * h + 1] = a.y * inv;
        y[4 * h + 2] = a.z * inv; y[4 * h + 3] = a.w * inv;
        mu += (a.x + a.y + a.z + a.w) * inv;
    }
    mu *= (1.f / NHID);
    float var = 0.f;
    #pragma unroll
    for (int j = 0; j < NHID; ++j) { float d = y[j] - mu; var += d * d; }
    var *= (1.f / NHID);
    const float rstd = rsqrtf(var + 1e-5f);
    #pragma unroll
    for (int j = 0; j < NHID; ++j) y[j] = (y[j] - mu) * rstd * lnw[j] + lnb[j];

    float o[NIN];
    #pragma unroll
    for (int i = 0; i < NIN; ++i) {
        float a = b1[i];
        #pragma unroll
        for (int j = 0; j < NHID; ++j) a += y[j] * W1[j * NIN + i];
        o[i] = fmaxf(a, 0.f) + inp[r * NIN + i];
        outp[r * NIN + i] = o[i];
    }

    const float rs7l2e = 0.3779644730092272f * 1.4426950408889634f;  // (1/sqrt7)*log2e
    float* K2Tb = K2T + ((size_t)b * NHID) * SS + s;
    float4* Q2r = (float4*)Q2 + (size_t)r * 7;
    #pragma unroll
    for (int j4 = 0; j4 < 7; ++j4) {
        float qq[4];
        #pragma unroll
        for (int c = 0; c < 4; ++c) {
            int j = 4 * j4 + c;
            float aq = bq2[j], ak = bk2[j];
            #pragma unroll
            for (int i = 0; i < NIN; ++i) {
                aq += o[i] * Wq2[i * NHID + j];
                ak += o[i] * Wk2[i * NHID + j];
            }
            qq[c] = aq * rs7l2e;
            K2Tb[(size_t)j * SS] = ak;      // coalesced per-j
        }
        Q2r[j4] = make_float4(qq[0], qq[1], qq[2], qq[3]);
    }
}

// ---------------------------------------------------------------------------
// Kernel 4: attention 2 weights. Wave-autonomous, 4 rows/wave; dynamic
// 28-dim loop (q via LDS scalar broadcast) + __launch_bounds__(256,4).
// Packed accumulators (8 pk_fma per r,d); per-component accumulation order
// preserved. exp2 softmax (Q2 pre-scaled by log2e in k_lnffn).
// Near its dual floor: ~12us VALU issue + ~11us HBM write of out2 (67MB).
// ---------------------------------------------------------------------------
#define QR 4
__global__ __launch_bounds__(256, 4) void k_attn2(
    const float* __restrict__ Q2, const float* __restrict__ K2T,
    float* __restrict__ out2)
{
    __shared__ float q2s[16 * NHID];   // 1792 B

    const int tid  = threadIdx.x;
    const int lane = tid & 63;
    const int wid  = tid >> 6;
    const int row0 = blockIdx.x * 16;          // global row = b*1024 + s
    const int b    = row0 >> 10;

    if (tid < 112) ((float4*)q2s)[tid] = ((const float4*)Q2)[(size_t)row0 * 7 + tid];
    __syncthreads();

    const float*  qw  = q2s + wid * QR * NHID;              // this wave's 4 rows
    const float4* K2b = (const float4*)(K2T + (size_t)b * NHID * SS);  // [28][256] f4

    v2f plo[4][QR], phi[4][QR];    // [col-block][row]: 64 VGPRs total
    #pragma unroll
    for (int cb = 0; cb < 4; ++cb)
        #pragma unroll
        for (int r = 0; r < QR; ++r) { plo[cb][r] = splat2(0.f); phi[cb][r] = splat2(0.f); }

    #pragma unroll 2
    for (int d = 0; d < NHID; ++d) {
        const float4 kt0 = K2b[d * 256 +       lane];
        const float4 kt1 = K2b[d * 256 +  64 + lane];
        const float4 kt2 = K2b[d * 256 + 128 + lane];
        const float4 kt3 = K2b[d * 256 + 192 + lane];
        const v2f k0l = lo2(kt0), k0h = hi2(kt0);
        const v2f k1l = lo2(kt1), k1h = hi2(kt1);
        const v2f k2l = lo2(kt2), k2h = hi2(kt2);
        const v2f k3l = lo2(kt3), k3h = hi2(kt3);
        #pragma unroll
        for (int r = 0; r < QR; ++r) {
            const v2f qd2 = splat2(qw[r * NHID + d]);  // LDS scalar broadcast
            plo[0][r] = pkfma(qd2, k0l, plo[0][r]); phi[0][r] = pkfma(qd2, k0h, phi[0][r]);
            plo[1][r] = pkfma(qd2, k1l, plo[1][r]); phi[1][r] = pkfma(qd2, k1h, phi[1][r]);
            plo[2][r] = pkfma(qd2, k2l, plo[2][r]); phi[2][r] = pkfma(qd2, k2h, phi[2][r]);
            plo[3][r] = pkfma(qd2, k3l, plo[3][r]); phi[3][r] = pkfma(qd2, k3h, phi[3][r]);
        }
    }

    #pragma unroll
    for (int r = 0; r < QR; ++r) {
        #pragma unroll
        for (int cb = 0; cb < 4; ++cb) {
            plo[cb][r].x = EXP2F(plo[cb][r].x); plo[cb][r].y = EXP2F(plo[cb][r].y);
            phi[cb][r].x = EXP2F(phi[cb][r].x); phi[cb][r].y = EXP2F(phi[cb][r].y);
        }
        // same left-assoc chain order as before (lo.x, lo.y, hi.x, hi.y per cb)
        float sum = plo[0][r].x + plo[0][r].y + phi[0][r].x + phi[0][r].y
                  + plo[1][r].x + plo[1][r].y + phi[1][r].x + phi[1][r].y
                  + plo[2][r].x + plo[2][r].y + phi[2][r].x + phi[2][r].y
                  + plo[3][r].x + plo[3][r].y + phi[3][r].x + phi[3][r].y;
        #pragma unroll
        for (int off = 1; off < 64; off <<= 1) sum += __shfl_xor(sum, off);
        const float iv = 1.f / sum;
        float4* orow = (float4*)(out2 + ((size_t)row0 + wid * QR + r) * SS);
        #pragma unroll
        for (int cb = 0; cb < 4; ++cb)
            orow[cb * 64 + lane] = make_float4(plo[cb][r].x * iv, plo[cb][r].y * iv,
                                               phi[cb][r].x * iv, phi[cb][r].y * iv);
    }
}

// ---------------------------------------------------------------------------
extern "C" void kernel_launch(void* const* d_in, const int* in_sizes, int n_in,
                              void* d_out, int out_size, void* d_ws, size_t ws_size,
                              hipStream_t stream) {
    const float* inp = (const float*)d_in[0];
    const float* Wq  = (const float*)d_in[1];
    const float* bq  = (const float*)d_in[2];
    const float* Wk  = (const float*)d_in[3];
    const float* bk  = (const float*)d_in[4];
    const float* Wv  = (const float*)d_in[5];
    const float* bv  = (const float*)d_in[6];
    const float* lnw = (const float*)d_in[7];
    const float* lnb = (const float*)d_in[8];
    const float* W1  = (const float*)d_in[9];
    const float* b1  = (const float*)d_in[10];
    const float* Wq2 = (const float*)d_in[11];
    const float* bq2 = (const float*)d_in[12];
    const float* Wk2 = (const float*)d_in[13];
    const float* bk2 = (const float*)d_in[14];

    float* out0 = (float*)d_out;                 // [16,1024,7]
    float* out2 = out0 + ROWS * NIN;             // [16,1024,1024]

    // Split-K partials live in the out2 region (16.7M floats); k_attn2
    // overwrites it afterwards. Apart: 458752 float4 (=4*QKV_ELEMS floats),
    // Lpart: 458752 floats -> 2.29M floats total, fits easily.
    float4* Apart = (float4*)out2;
    float*  Lpart = out2 + (size_t)4 * QKV_ELEMS;

    float* ws = (float*)d_ws;
    float* Q2  = ws;
    float* K2T = ws + (size_t)QKV_ELEMS;         // [B,28,S]

    k_attn1<<<BB * NH * 16, 512, 0, stream>>>(inp, Wq, bq, Wk, bk, Wv, bv,
                                              Apart, Lpart);
    k_lnffn<<<ROWS / 256, 256, 0, stream>>>(Apart, Lpart, inp, lnw, lnb, W1, b1,
                                            Wq2, bq2, Wk2, bk2, out0, Q2, K2T);
    k_attn2<<<ROWS / 16, 256, 0, stream>>>(Q2, K2T, out2);
}

// Round 9
// 170.101 us; speedup vs baseline: 1.0268x; 1.0268x over previous
//
#include <hip/hip_runtime.h>

// Problem constants (fixed by reference)
#define BB 16
#define SS 1024
#define NIN 7
#define NHID 28
#define NH 7
#define DH 4

// Raw 2^x (v_exp_f32). exp(x) == exp2(x*log2e); log2e folded into Q scales.
#define EXP2F(x) __builtin_amdgcn_exp2f(x)

// Packed fp32 (VOP3P v_pk_mul_f32 / v_pk_fma_f32).
typedef float v2f __attribute__((ext_vector_type(2)));
__device__ __forceinline__ v2f pkfma(v2f a, v2f b, v2f c) {
    return __builtin_elementwise_fma(a, b, c);
}
__device__ __forceinline__ v2f lo2(float4 a) { v2f r; r.x = a.x; r.y = a.y; return r; }
__device__ __forceinline__ v2f hi2(float4 a) { v2f r; r.x = a.z; r.y = a.w; return r; }
__device__ __forceinline__ v2f splat2(float s) { v2f r; r.x = s; r.y = s; return r; }

constexpr int ROWS = BB * SS;                 // 16384
constexpr int QKV_ELEMS = BB * NH * SS * DH;  // 458752 floats per tensor
constexpr int CHUNK_STRIDE = BB * NH * SS;    // 114688: per-ks-chunk stride (f4 / f1 units)

// ---------------------------------------------------------------------------
// Kernel 1 (fused): attention 1 WITH in-block QKV projection.
// == EXACT REVERT TO R6 (measured best: total 167.9us, attn1 ~40us) ==
//
// Constraint triangle pinned by measured failures -- do not re-cross:
//  - R7: quad-consecutive query ownership -> 64B/lane LDS write stride ->
//    2.06M bank-conflict cycles. Interleaved (r*64+ql) ownership is sacred.
//  - R8: transposed-K packed dot cut issue (busy 33.5->26us) but hoisted
//    splats pushed VGPR 44->68, crossing the 64-VGPR occupancy cliff
//    (m69: waves/CU halves at vgpr=64): occupancy 50->19%, wall 40->49us.
//    VGPR <= 64 is sacred for this 512-thread kernel.
//  - R1: per-iteration s_load K/V serializes on SMEM latency. LDS
//    broadcast ds_read is the right K/V path.
//
// Design: weights/biases via block-uniform s_load (SGPR operands, one-time
// prologue); x rows read directly from global (L1/L2-hot); K/V projected
// cooperatively (256 thr K, 256 thr V) into 8KB LDS; per-thread Q proj for
// 4 interleaved queries; 8 waves x 32-key slices, broadcast ds_read_b128;
// in-block 8-slice merge; unnormalized per-(q,ks) partials to scratch in
// the out2 region (k_attn2 overwrites it later -- safe by stream order).
// Split-K x4: grid = 112 bh x 4 qt x 4 ks = 1792 == 7/CU. 3 barriers.
// All FP chain orders fixed since R5 -> absmax exactly 0.001953125.
// ---------------------------------------------------------------------------
__global__ __launch_bounds__(512) void k_attn1(
    const float* __restrict__ inp,
    const float* __restrict__ Wq, const float* __restrict__ bq,
    const float* __restrict__ Wk, const float* __restrict__ bk,
    const float* __restrict__ Wv, const float* __restrict__ bv,
    float4* __restrict__ Apart, float* __restrict__ Lpart)
{
    __shared__ char smem[40960];
    float4* Ksh  = (float4*)smem;             // [256]   4 KB (phase 1)
    float4* Vsh  = (float4*)(smem + 4096);    // [256]   4 KB (phase 1)
    float4* pacc = (float4*)smem;             // [8][256] 32 KB (phase 2 overlay)
    float*  pl   = (float*)(smem + 32768);    // [8][256]  8 KB

    const int bh  = blockIdx.x >> 4;          // 0..111
    const int qt  = (blockIdx.x >> 2) & 3;    // q tile (256 queries)
    const int ks  = blockIdx.x & 3;           // key chunk (256 keys)
    const int tid = threadIdx.x;
    const int b   = bh / NH, h = bh % NH;

    const int ql = tid & 63;
    const int kq = tid >> 6;          // wave id; uniform within wave

    // ---- cooperative K/V projection straight from global x (L1/L2-hot):
    //      threads 0-255 -> K key tid, threads 256-511 -> V key tid-256.
    //      Weight/bias indices are block-uniform -> s_load (SGPR).
    {
        const int half = __builtin_amdgcn_readfirstlane(tid >> 8);  // 0:K 1:V
        const int key  = tid & 255;
        const float* xr = inp + (size_t)(b * SS + (ks << 8) + key) * NIN;
        const float* W  = half ? Wv : Wk;
        const float4 bias = ((const float4*)(half ? bv : bk))[h];
        v2f alo = lo2(bias), ahi = hi2(bias);
        #pragma unroll
        for (int i = 0; i < NIN; ++i) {
            const v2f xi2 = splat2(xr[i]);
            const float4 w = ((const float4*)W)[i * NH + h];   // uniform -> SGPR
            alo = pkfma(xi2, lo2(w), alo);
            ahi = pkfma(xi2, hi2(w), ahi);
        }
        const float4 kv = make_float4(alo.x, alo.y, ahi.x, ahi.y);
        if (half == 0) Ksh[key] = kv;
        else           Vsh[key] = kv;
    }

    // ---- per-thread Q projection for the 4 owned queries (independent of
    //      LDS; overlaps the K/V LDS writes). Same fma order as before.
    const float qs_scale = 0.5f * 1.4426950408889634f;  // (1/sqrt(4)) * log2(e)
    const v2f qs2 = splat2(qs_scale);
    const float4 bq4 = ((const float4*)bq)[h];           // uniform -> SGPR
    v2f qlo[4], qhi[4];
    #pragma unroll
    for (int r = 0; r < 4; ++r) {
        const float* xr = inp + (size_t)(b * SS + (qt << 8) + r * 64 + ql) * NIN;
        v2f alo = lo2(bq4), ahi = hi2(bq4);
        #pragma unroll
        for (int i = 0; i < NIN; ++i) {
            const v2f xi2 = splat2(xr[i]);
            const float4 w = ((const float4*)Wq)[i * NH + h]; // uniform -> SGPR
            alo = pkfma(xi2, lo2(w), alo);
            ahi = pkfma(xi2, hi2(w), ahi);
        }
        qlo[r] = alo * qs2;
        qhi[r] = ahi * qs2;
    }
    __syncthreads();   // K/V visible to all waves

    v2f alo[4], ahi[4];
    float l[4];
    #pragma unroll
    for (int r = 0; r < 4; ++r) {
        alo[r] = splat2(0.f); ahi[r] = splat2(0.f); l[r] = 0.f;
    }

    const int k0 = kq << 5;
    #pragma unroll 4
    for (int kk = k0; kk < k0 + 32; ++kk) {
        const float4 kr = Ksh[kk];    // single broadcast addr per wave
        const float4 vr = Vsh[kk];
        const v2f klo = lo2(kr), khi = hi2(kr);
        const v2f vlo = lo2(vr), vhi = hi2(vr);
        #pragma unroll
        for (int r = 0; r < 4; ++r) {
            v2f t = qlo[r] * klo;             // v_pk_mul_f32
            t = pkfma(qhi[r], khi, t);        // v_pk_fma_f32
            const float s = t.x + t.y;
            const float p = EXP2F(s);
            l[r] += p;
            const v2f pp = splat2(p);
            alo[r] = pkfma(pp, vlo, alo[r]);
            ahi[r] = pkfma(pp, vhi, ahi[r]);
        }
    }

    __syncthreads();   // all K/V reads done; smem reused as merge buffers
    #pragma unroll
    for (int r = 0; r < 4; ++r) {
        pacc[kq * 256 + r * 64 + ql] = make_float4(alo[r].x, alo[r].y,
                                                   ahi[r].x, ahi[r].y);
        pl[kq * 256 + r * 64 + ql]   = l[r];
    }
    __syncthreads();

    // merge the 8 k-slices: threads 0..255 own query qt*256 + tid
    if (tid < 256) {
        float4 a0 = pacc[tid];
        v2f mlo = lo2(a0), mhi = hi2(a0);
        float ll = pl[tid];
        #pragma unroll
        for (int j = 1; j < 8; ++j) {
            const float4 t = pacc[j * 256 + tid];
            mlo = mlo + lo2(t);               // v_pk_add_f32, per-comp order
            mhi = mhi + hi2(t);
            ll += pl[j * 256 + tid];
        }
        // unnormalized partial for this 256-key chunk; coalesced in q
        const size_t o = ((size_t)(ks * (BB * NH) + bh) << 10) + (qt << 8) + tid;
        Apart[o] = make_float4(mlo.x, mlo.y, mhi.x, mhi.y);
        Lpart[o] = ll;
    }
}

// ---------------------------------------------------------------------------
// Kernel 3: reduce the 4 split-K partials + normalize (softmax denominator),
// then LayerNorm(28) + FFN(28->7)+ReLU+residual -> out (output 0),
// then Q2 (row-major, pre-scaled by (1/sqrt(7))*log2e for exp2 softmax)
// and K2 TRANSPOSED: K2T[b][d][s].
// ---------------------------------------------------------------------------
__global__ __launch_bounds__(256) void k_lnffn(
    const float4* __restrict__ Apart, const float* __restrict__ Lpart,
    const float* __restrict__ inp,
    const float* __restrict__ lnw, const float* __restrict__ lnb,
    const float* __restrict__ W1, const float* __restrict__ b1,
    const float* __restrict__ Wq2, const float* __restrict__ bq2,
    const float* __restrict__ Wk2, const float* __restrict__ bk2,
    float* __restrict__ outp, float* __restrict__ Q2, float* __restrict__ K2T)
{
    const int r = blockIdx.x * 256 + threadIdx.x;
    const int b = r >> 10, s = r & 1023;

    float y[NHID];
    float mu = 0.f;
    #pragma unroll
    for (int h = 0; h < NH; ++h) {
        const size_t base = ((size_t)(b * NH + h) << 10) + s;
        float4 a  = Apart[base];
        float  ll = Lpart[base];
        #pragma unroll
        for (int c = 1; c < 4; ++c) {
            float4 t = Apart[base + (size_t)c * CHUNK_STRIDE];
            a.x += t.x; a.y += t.y; a.z += t.z; a.w += t.w;
            ll += Lpart[base + (size_t)c * CHUNK_STRIDE];
        }
        const float inv = 1.f / ll;
        y[4 * h + 0] = a.x * inv; y[4 * h + 1] = a.y * inv;
        y[4 * h + 2] = a.z * inv; y[4 * h + 3] = a.w * inv;
        mu += (a.x + a.y + a.z + a.w) * inv;
    }
    mu *= (1.f / NHID);
    float var = 0.f;
    #pragma unroll
    for (int j = 0; j < NHID; ++j) { float d = y[j] - mu; var += d * d; }
    var *= (1.f / NHID);
    const float rstd = rsqrtf(var + 1e-5f);
    #pragma unroll
    for (int j = 0; j < NHID; ++j) y[j] = (y[j] - mu) * rstd * lnw[j] + lnb[j];

    float o[NIN];
    #pragma unroll
    for (int i = 0; i < NIN; ++i) {
        float a = b1[i];
        #pragma unroll
        for (int j = 0; j < NHID; ++j) a += y[j] * W1[j * NIN + i];
        o[i] = fmaxf(a, 0.f) + inp[r * NIN + i];
        outp[r * NIN + i] = o[i];
    }

    const float rs7l2e = 0.3779644730092272f * 1.4426950408889634f;  // (1/sqrt7)*log2e
    float* K2Tb = K2T + ((size_t)b * NHID) * SS + s;
    float4* Q2r = (float4*)Q2 + (size_t)r * 7;
    #pragma unroll
    for (int j4 = 0; j4 < 7; ++j4) {
        float qq[4];
        #pragma unroll
        for (int c = 0; c < 4; ++c) {
            int j = 4 * j4 + c;
            float aq = bq2[j], ak = bk2[j];
            #pragma unroll
            for (int i = 0; i < NIN; ++i) {
                aq += o[i] * Wq2[i * NHID + j];
                ak += o[i] * Wk2[i * NHID + j];
            }
            qq[c] = aq * rs7l2e;
            K2Tb[(size_t)j * SS] = ak;      // coalesced per-j
        }
        Q2r[j4] = make_float4(qq[0], qq[1], qq[2], qq[3]);
    }
}

// ---------------------------------------------------------------------------
// Kernel 4: attention 2 weights. Wave-autonomous, 4 rows/wave; dynamic
// 28-dim loop (q via LDS scalar broadcast) + __launch_bounds__(256,4).
// Packed accumulators (8 pk_fma per r,d); per-component accumulation order
// preserved. exp2 softmax (Q2 pre-scaled by log2e in k_lnffn).
// Near its dual floor: ~12us VALU issue + ~11us HBM write of out2 (67MB).
// ---------------------------------------------------------------------------
#define QR 4
__global__ __launch_bounds__(256, 4) void k_attn2(
    const float* __restrict__ Q2, const float* __restrict__ K2T,
    float* __restrict__ out2)
{
    __shared__ float q2s[16 * NHID];   // 1792 B

    const int tid  = threadIdx.x;
    const int lane = tid & 63;
    const int wid  = tid >> 6;
    const int row0 = blockIdx.x * 16;          // global row = b*1024 + s
    const int b    = row0 >> 10;

    if (tid < 112) ((float4*)q2s)[tid] = ((const float4*)Q2)[(size_t)row0 * 7 + tid];
    __syncthreads();

    const float*  qw  = q2s + wid * QR * NHID;              // this wave's 4 rows
    const float4* K2b = (const float4*)(K2T + (size_t)b * NHID * SS);  // [28][256] f4

    v2f plo[4][QR], phi[4][QR];    // [col-block][row]: 64 VGPRs total
    #pragma unroll
    for (int cb = 0; cb < 4; ++cb)
        #pragma unroll
        for (int r = 0; r < QR; ++r) { plo[cb][r] = splat2(0.f); phi[cb][r] = splat2(0.f); }

    #pragma unroll 2
    for (int d = 0; d < NHID; ++d) {
        const float4 kt0 = K2b[d * 256 +       lane];
        const float4 kt1 = K2b[d * 256 +  64 + lane];
        const float4 kt2 = K2b[d * 256 + 128 + lane];
        const float4 kt3 = K2b[d * 256 + 192 + lane];
        const v2f k0l = lo2(kt0), k0h = hi2(kt0);
        const v2f k1l = lo2(kt1), k1h = hi2(kt1);
        const v2f k2l = lo2(kt2), k2h = hi2(kt2);
        const v2f k3l = lo2(kt3), k3h = hi2(kt3);
        #pragma unroll
        for (int r = 0; r < QR; ++r) {
            const v2f qd2 = splat2(qw[r * NHID + d]);  // LDS scalar broadcast
            plo[0][r] = pkfma(qd2, k0l, plo[0][r]); phi[0][r] = pkfma(qd2, k0h, phi[0][r]);
            plo[1][r] = pkfma(qd2, k1l, plo[1][r]); phi[1][r] = pkfma(qd2, k1h, phi[1][r]);
            plo[2][r] = pkfma(qd2, k2l, plo[2][r]); phi[2][r] = pkfma(qd2, k2h, phi[2][r]);
            plo[3][r] = pkfma(qd2, k3l, plo[3][r]); phi[3][r] = pkfma(qd2, k3h, phi[3][r]);
        }
    }

    #pragma unroll
    for (int r = 0; r < QR; ++r) {
        #pragma unroll
        for (int cb = 0; cb < 4; ++cb) {
            plo[cb][r].x = EXP2F(plo[cb][r].x); plo[cb][r].y = EXP2F(plo[cb][r].y);
            phi[cb][r].x = EXP2F(phi[cb][r].x); phi[cb][r].y = EXP2F(phi[cb][r].y);
        }
        // same left-assoc chain order as before (lo.x, lo.y, hi.x, hi.y per cb)
        float sum = plo[0][r].x + plo[0][r].y + phi[0][r].x + phi[0][r].y
                  + plo[1][r].x + plo[1][r].y + phi[1][r].x + phi[1][r].y
                  + plo[2][r].x + plo[2][r].y + phi[2][r].x + phi[2][r].y
                  + plo[3][r].x + plo[3][r].y + phi[3][r].x + phi[3][r].y;
        #pragma unroll
        for (int off = 1; off < 64; off <<= 1) sum += __shfl_xor(sum, off);
        const float iv = 1.f / sum;
        float4* orow = (float4*)(out2 + ((size_t)row0 + wid * QR + r) * SS);
        #pragma unroll
        for (int cb = 0; cb < 4; ++cb)
            orow[cb * 64 + lane] = make_float4(plo[cb][r].x * iv, plo[cb][r].y * iv,
                                               phi[cb][r].x * iv, phi[cb][r].y * iv);
    }
}

// ---------------------------------------------------------------------------
extern "C" void kernel_launch(void* const* d_in, const int* in_sizes, int n_in,
                              void* d_out, int out_size, void* d_ws, size_t ws_size,
                              hipStream_t stream) {
    const float* inp = (const float*)d_in[0];
    const float* Wq  = (const float*)d_in[1];
    const float* bq  = (const float*)d_in[2];
    const float* Wk  = (const float*)d_in[3];
    const float* bk  = (const float*)d_in[4];
    const float* Wv  = (const float*)d_in[5];
    const float* bv  = (const float*)d_in[6];
    const float* lnw = (const float*)d_in[7];
    const float* lnb = (const float*)d_in[8];
    const float* W1  = (const float*)d_in[9];
    const float* b1  = (const float*)d_in[10];
    const float* Wq2 = (const float*)d_in[11];
    const float* bq2 = (const float*)d_in[12];
    const float* Wk2 = (const float*)d_in[13];
    const float* bk2 = (const float*)d_in[14];

    float* out0 = (float*)d_out;                 // [16,1024,7]
    float* out2 = out0 + ROWS * NIN;             // [16,1024,1024]

    // Split-K partials live in the out2 region (16.7M floats); k_attn2
    // overwrites it afterwards. Apart: 458752 float4 (=4*QKV_ELEMS floats),
    // Lpart: 458752 floats -> 2.29M floats total, fits easily.
    float4* Apart = (float4*)out2;
    float*  Lpart = out2 + (size_t)4 * QKV_ELEMS;

    float* ws = (float*)d_ws;
    float* Q2  = ws;
    float* K2T = ws + (size_t)QKV_ELEMS;         // [B,28,S]

    k_attn1<<<BB * NH * 16, 512, 0, stream>>>(inp, Wq, bq, Wk, bk, Wv, bv,
                                              Apart, Lpart);
    k_lnffn<<<ROWS / 256, 256, 0, stream>>>(Apart, Lpart, inp, lnw, lnb, W1, b1,
                                            Wq2, bq2, Wk2, bk2, out0, Q2, K2T);
    k_attn2<<<ROWS / 16, 256, 0, stream>>>(Q2, K2T, out2);
}